// Round 14
// baseline (670.004 us; speedup 1.0000x reference)
//
#include <hip/hip_runtime.h>
#include <stdint.h>

typedef __bf16 bf16x8 __attribute__((ext_vector_type(8)));
typedef float f32x4 __attribute__((ext_vector_type(4)));
typedef uint16_t u16;
typedef uint32_t u32;
typedef u16 u16x8 __attribute__((ext_vector_type(8)));

#define NSTEP 63   // 2*32-1 diagonal steps

// ---- workspace layout (bytes) ----
#define IMG_SK_BYTES (128ull*NSTEP*4096ull*2ull)
#define WPACK_OFF    IMG_SK_BYTES
#define BIAS_OFF     (WPACK_OFF + 512ull*384ull*2ull)
#define FX_OFF       (BIAS_OFF + 2048ull)
#define TMP_OFF      (FX_OFF + 2048ull)

// ---- helpers ----
__device__ __forceinline__ u16 f2bf(float f) {
  u32 u = __builtin_bit_cast(u32, f);
  return (u16)((u + 0x7fffu + ((u >> 16) & 1u)) >> 16);   // RNE
}
__device__ __forceinline__ float bf2f(u16 h) {
  u32 u = ((u32)h) << 16;
  return __builtin_bit_cast(float, u);
}
__device__ __forceinline__ float sigf(float x) {
  float e = __builtin_amdgcn_exp2f(-1.442695041f * x);
  return __builtin_amdgcn_rcpf(1.0f + e);
}
__device__ __forceinline__ float tanhf_fast(float x) {
  x = fminf(fmaxf(x, -20.f), 20.f);       // clamp: avoid inf-inf NaN
  float e = __builtin_amdgcn_exp2f(2.885390082f * x);
  return (e - 1.0f) * __builtin_amdgcn_rcpf(e + 1.0f);
}
__device__ __forceinline__ void gload_lds16(const void* g, char* smem, u32 lds_off) {
  __builtin_amdgcn_global_load_lds(
      (const __attribute__((address_space(1))) uint32_t*)g,
      (__attribute__((address_space(3))) uint32_t*)(smem + lds_off), 16, 0, 0);
}
__device__ __forceinline__ bf16x8 ldsv(const char* smem, u32 off) {
  return *reinterpret_cast<const bf16x8*>(smem + off);    // ds_read_b128
}

// =====================================================================
// Kernel 1: pre-skew image (R1..R12-passing verbatim).
// =====================================================================
__global__ __launch_bounds__(256) void k_prepack_img(
    const float* __restrict__ image, u16* __restrict__ img_sk) {
  __shared__ float tile[128 * 33];
  const int b = blockIdx.x >> 5, n = blockIdx.x & 31;
  const int tid = threadIdx.x;
  for (int rep = 0; rep < 16; ++rep) {
    int idx = rep * 256 + tid;
    int c = idx >> 5, col = idx & 31;
    tile[c * 33 + col] = image[(((b * 128 + c) * 32 + n) << 5) + col];
  }
  __syncthreads();
  const int m = n & 7;
  for (int rep = 0; rep < 4; ++rep) {
    int idx = rep * 256 + tid;
    if (idx < NSTEP * 16) {
      int t = idx >> 4, six = idx & 15;
      bool valid = (t >= n) && (t < n + 32);
      u16x8 v;
      #pragma unroll
      for (int j = 0; j < 8; ++j) {
        int c = ((six ^ m) << 3) | j;              // inverse of read-side XOR swizzle
        v[j] = valid ? f2bf(tile[c * 33 + (t - n)]) : (u16)0;
      }
      *reinterpret_cast<u16x8*>(img_sk + (size_t)(b * NSTEP + t) * 4096 + n * 128 + six * 8) = v;
    }
  }
}

// =====================================================================
// Kernel 2: pack W, 8-wave geometry (R1..R12-passing verbatim).
// =====================================================================
__global__ __launch_bounds__(256) void k_prepack_w(
    const float* __restrict__ stos_w, const float* __restrict__ itos_w,
    u16* __restrict__ wp) {
  int pos = blockIdx.x * 256 + threadIdx.x;        // [w][mt][kk][lane][j]
  int j = pos & 7, l = (pos >> 3) & 63;
  int kk = (pos >> 9) % 12;
  int mtw = pos / 6144;
  int mt = mtw & 3, w = mtw >> 2;
  int r16 = l & 15;
  int q = r16 & 3, p = r16 >> 2;
  int c = w * 16 + mt * 4 + p;
  int o = q * 128 + c;
  int k = kk * 32 + (l >> 4) * 8 + j;
  float v;
  if (k < 128)       v = stos_w[o * 256 + k * 2 + 0];
  else if (k < 256)  v = stos_w[o * 256 + (k - 128) * 2 + 1];
  else               v = itos_w[o * 128 + (k - 256)];
  wp[pos] = f2bf(v);
}

__global__ void k_prepack_bias(const float* __restrict__ itos_b,
                               const float* __restrict__ stos_b,
                               float* __restrict__ bp) {
  int R = blockIdx.x * 256 + threadIdx.x;
  if (R >= 512) return;
  int q = R & 3, p = (R >> 2) & 3, mt = (R >> 4) & 3, w = R >> 6;
  int o = q * 128 + (w * 16 + mt * 4 + p);
  bp[R] = itos_b[o] + stos_b[o];
}

// =====================================================================
// Kernel 3: diagonal-LSTM scan, N-SPLIT across 2 WGs per batch.
//   WG g: b = g>>1, half = g&1 owns columns s in [half*16, half*16+16).
//   Coupling is leftward only: WG1 needs h(t-1)[.,15], read from tmp
//   (WG0's un-deferred stores), gated by agent-scope flag fx[b] with
//   __threadfence() on both sides (cross-XCD L2 writeback/invalidate).
//   Per-WG step body is R12's verified structure at half the N.
// LDS map (static 114688 B):
//   [0,8448) hbuf0 | [8448,16896) hbuf1 | [16896,18944) bias(init only)
//   [32768,40960) imgbuf x2 (4KB each) | [49152,114688) A-frags kk=10,11
// =====================================================================
__global__ __attribute__((amdgpu_waves_per_eu(2, 2)))
__launch_bounds__(512, 2) void k_scan(
    const u16* __restrict__ img_sk, const u16* __restrict__ wpack,
    const float* __restrict__ biasp, const float* __restrict__ h0,
    const float* __restrict__ c0, u16* __restrict__ tmp, int* fx) {
  __shared__ char smem[114688];
  const int g = blockIdx.x;
  const int b = g >> 1, half = g & 1;
  const int tid = threadIdx.x;
  const int w = tid >> 6, lane = tid & 63;
  const int p = (lane >> 4) & 3, n0 = lane & 15;

  // ---- load A fragments kk 0..9 into registers (160 regs, R10/R12) ----
  bf16x8 aw[4][10];
  #pragma unroll
  for (int mt = 0; mt < 4; ++mt)
    #pragma unroll
    for (int kk = 0; kk < 10; ++kk)
      aw[mt][kk] = *reinterpret_cast<const bf16x8*>(
          wpack + (size_t)(((w * 4 + mt) * 12 + kk) * 64 + lane) * 8);
  // kk=10,11 A-frags -> LDS (once; W constant)
  #pragma unroll
  for (int mt = 0; mt < 4; ++mt) {
    gload_lds16(wpack + (size_t)(((w * 4 + mt) * 12 + 10) * 64 + lane) * 8,
                smem, 49152u + (u32)w * 8192u + (u32)mt * 2048u);
    gload_lds16(wpack + (size_t)(((w * 4 + mt) * 12 + 11) * 64 + lane) * 8,
                smem, 49152u + (u32)w * 8192u + (u32)mt * 2048u + 1024u);
  }
  // preload imgbuf[0]: this half's 16 rows (4KB), local layout rows 0..15.
  // Global row 16+n0 has (16+n0)&7 == n0&7, so the prepacked swizzle is
  // position-independent between halves.
  const u16* img_base = img_sk + (size_t)b * NSTEP * 4096 + (u32)half * 2048u;
  if (tid < 256)
    gload_lds16(img_base + (u32)tid * 8, smem, 32768u + (u32)w * 1024u);
  // bias -> LDS (staging only)
  ((float*)(smem + 16896))[tid] = biasp[tid & 511];
  // hbuf0 init: row 0 = zeros, rows 1..32 = h0 (swizzled) — verified formula
  for (int idx = tid; idx < 33 * 128; idx += 512) {
    int row = idx >> 7, c = idx & 127;
    u16 v = (row == 0) ? (u16)0 : f2bf(h0[c * 32 + (row - 1)]);
    u32 a = (u32)(row << 8) | (u32)((((c >> 3) ^ (row & 7)) << 4) | ((c & 7) << 1));
    *(u16*)(smem + a) = v;
  }
  // hbuf1 row 0 = zeros
  for (int idx = tid; idx < 128; idx += 512) {
    int c = idx;
    u32 a = 8448u + (u32)(((c >> 3) << 4) | ((c & 7) << 1));
    *(u16*)(smem + a) = (u16)0;
  }
  // c state (this half's columns)
  float cst[4];
  #pragma unroll
  for (int mt = 0; mt < 4; ++mt)
    cst[mt] = c0[(w * 16 + mt * 4 + p) * 32 + (half * 16 + n0)];

  // per-lane bases: half0 -> verified (Ls0,Lh0,Lw0); half1 -> (Ls1,Lh1,Lw1)
  const int nn = half * 16 + n0;
  const u32 Lsh = (u32)(nn << 8) ^ (u32)(p << 4) ^ (u32)((nn & 7) << 4);
  const u32 Lhh = (u32)((nn + 1) << 8) ^ (u32)(p << 4) ^ (u32)(((nn + 1) & 7) << 4);
  const u32 Lwh = (u32)((nn + 1) << 8) ^ (u32)(((nn + 1) & 7) << 4) ^ (u32)(w << 5) ^ (u32)(p << 1);
  const u32 Li  = (u32)(n0 << 8) ^ (u32)(p << 4) ^ (u32)((n0 & 7) << 4);  // local img rows
  const u32 tmpidx = (u32)((w * 16 + p) * 32 + half * 16 + n0);           // + mt*128
  u16* tmpb = tmp + (size_t)b * NSTEP * 4096;

  __syncthreads();   // init DMAs + LDS writes visible

  // bias into registers (once)
  f32x4 bias_r[4];
  #pragma unroll
  for (int mt = 0; mt < 4; ++mt)
    bias_r[mt] = *reinterpret_cast<const f32x4*>(smem + 16896 + ((w * 64 + mt * 16 + p * 4) << 2));

  f32x4 acc[4];
  u16 hb[4];

  #pragma unroll 1
  for (int t = 0; t < NSTEP; ++t) {
    const u32 hbb = (u32)((t & 1) ? 8448u : 0u);          // hbuf read base
    // ---- half1: import h(t-1)[.,15] from tmp into hbuf row 16 ----
    if (half && t) {
      if (tid == 0) {
        while (__hip_atomic_load(fx + b, __ATOMIC_RELAXED, __HIP_MEMORY_SCOPE_AGENT) < t)
          __builtin_amdgcn_s_sleep(1);
        __threadfence();   // agent acquire: invalidate L1/L2 before data loads
      }
      __syncthreads();
      if (tid < 128) {
        u16 v = tmpb[(size_t)(t - 1) * 4096 + (u32)tid * 32 + 15];
        u32 a = hbb + 4096u + (u32)(((tid >> 3) << 4) | ((tid & 7) << 1));  // row16, swz=0
        *(u16*)(smem + a) = v;
      }
      __syncthreads();
    }
    // prefetch next image column (this half's 4KB) into the other imgbuf
    if (t < NSTEP - 1 && tid < 256)
      gload_lds16(img_base + (size_t)(t + 1) * 4096 + (u32)tid * 8,
                  smem, 32768u + (u32)(((t + 1) & 1) << 12) + (u32)w * 1024u);
    // acc = bias (from registers)
    #pragma unroll
    for (int mt = 0; mt < 4; ++mt) acc[mt] = bias_r[mt];

    const u32 ib = 32768u + (u32)((t & 1) << 12);

    // ---- MFMA ladder: 12 kk x 4 mt = 48 MFMAs ----
    #pragma unroll
    for (int kk = 0; kk < 12; ++kk) {
      bf16x8 bv;
      if (kk < 4)      bv = ldsv(smem, hbb + (Lsh ^ (u32)(kk << 6)));        // shifted h
      else if (kk < 8) bv = ldsv(smem, hbb + (Lhh ^ (u32)((kk - 4) << 6)));  // h
      else             bv = ldsv(smem, ib + (Li ^ (u32)((kk - 8) << 6)));    // image
      #pragma unroll
      for (int mt = 0; mt < 4; ++mt) {
        bf16x8 a = (kk < 10) ? aw[mt][kk]
                             : ldsv(smem, 49152u + (u32)w * 8192u + (u32)mt * 2048u
                                        + (u32)((kk - 10) << 10) + (u32)lane * 16u);
        acc[mt] = __builtin_amdgcn_mfma_f32_16x16x32_bf16(a, bv, acc[mt], 0, 0, 0);
      }
    }
    // ---- activations (regs j = i,g,f,o of one (c,s)) ----
    #pragma unroll
    for (int mt = 0; mt < 4; ++mt) {
      f32x4 g4 = acc[mt];
      float si = sigf(g4[0]);
      float tg = tanhf_fast(g4[1]);
      float sf = sigf(g4[2]);
      float so = sigf(g4[3]);
      float cp = cst[mt];
      cst[mt] = sf * cp + si * tg;     // c_new
      hb[mt] = f2bf(cp * so);          // h_new = c_prev * sig(o)  (per reference)
    }
    // tmp stores (un-deferred: must precede the barrier for the publish)
    #pragma unroll
    for (int mt = 0; mt < 4; ++mt)
      tmpb[(size_t)t * 4096 + tmpidx + mt * 128] = hb[mt];
    // write h(t) into the OTHER hbuf (rows s+1)
    {
      const u32 hwb = (u32)((t & 1) ? 0u : 8448u);
      #pragma unroll
      for (int mt = 0; mt < 4; ++mt) {
        u32 a = hwb + (Lwh ^ (u32)((mt >= 2) ? 16u : 0u) ^ (u32)((mt & 1) << 3));
        *(u16*)(smem + a) = hb[mt];
      }
    }
    __syncthreads();   // h(t) + img(t+1) visible; tmp stores drained (vmcnt)
    // ---- half0: publish h(0..t) available in tmp ----
    if (half == 0 && tid == 0) {
      __threadfence();   // agent release: write back L2 so the other XCD sees tmp
      __hip_atomic_store(fx + b, t + 1, __ATOMIC_RELAXED, __HIP_MEMORY_SCOPE_AGENT);
    }
  }
}

// =====================================================================
// Kernel 4: unskew-transpose tmp -> out (R3..R12-passing verbatim).
// =====================================================================
__global__ __launch_bounds__(256) void k_unskew(
    const u16* __restrict__ tmp, float* __restrict__ out) {
  __shared__ float tile[8192];                 // [cl][s][j] = cl*1024+s*32+j
  const int b = blockIdx.x >> 4, c8 = blockIdx.x & 15;
  const int tid = threadIdx.x;
  const int cl = tid >> 5, s = tid & 31;
  const u16* tb = tmp + (size_t)b * NSTEP * 4096 + (u32)(c8 * 256 + cl * 32 + s);
  for (int t = 0; t < NSTEP; ++t) {
    u16 v = tb[t * 4096];
    int j = t - s;
    if ((unsigned)j < 32u) tile[cl * 1024 + s * 32 + j] = bf2f(v);
  }
  __syncthreads();
  float* op = out + (size_t)b * 131072 + (u32)(c8 * 8192);
  #pragma unroll
  for (int rep = 0; rep < 8; ++rep)
    *(f32x4*)(op + rep * 1024 + tid * 4) = *(const f32x4*)(tile + rep * 1024 + tid * 4);
}

// =====================================================================
extern "C" void kernel_launch(void* const* d_in, const int* in_sizes, int n_in,
                              void* d_out, int out_size, void* d_ws, size_t ws_size,
                              hipStream_t stream) {
  const float* image  = (const float*)d_in[0];
  const float* itos_w = (const float*)d_in[1];
  const float* itos_b = (const float*)d_in[2];
  const float* stos_w = (const float*)d_in[3];
  const float* stos_b = (const float*)d_in[4];
  const float* h0     = (const float*)d_in[5];
  const float* c0     = (const float*)d_in[6];
  (void)in_sizes; (void)n_in; (void)out_size; (void)ws_size;

  char* ws = (char*)d_ws;
  u16*   img_sk = (u16*)(ws);
  u16*   wpack  = (u16*)(ws + WPACK_OFF);
  float* biasp  = (float*)(ws + BIAS_OFF);
  int*   fx     = (int*)(ws + FX_OFF);
  u16*   tmp    = (u16*)(ws + TMP_OFF);

  hipMemsetAsync(fx, 0, 512, stream);   // flags must be 0 every launch (graph replay)
  k_prepack_img <<<4096, 256, 0, stream>>>(image, img_sk);
  k_prepack_w   <<<768, 256, 0, stream>>>(stos_w, itos_w, wpack);
  k_prepack_bias<<<2, 256, 0, stream>>>(itos_b, stos_b, biasp);
  k_scan        <<<256, 512, 0, stream>>>(img_sk, wpack, biasp, h0, c0, tmp, fx);
  k_unskew      <<<2048, 256, 0, stream>>>(tmp, (float*)d_out);
}

// Round 15
// 243.828 us; speedup vs baseline: 2.7479x; 2.7479x over previous
//
#include <hip/hip_runtime.h>
#include <stdint.h>

typedef __bf16 bf16x8 __attribute__((ext_vector_type(8)));
typedef float f32x4 __attribute__((ext_vector_type(4)));
typedef uint16_t u16;
typedef uint32_t u32;
typedef u16 u16x8 __attribute__((ext_vector_type(8)));

#define NSTEP 63   // 2*32-1 diagonal steps

// ---- workspace layout (bytes) ----
#define IMG_SK_BYTES (128ull*NSTEP*4096ull*2ull)
#define WPACK_OFF    IMG_SK_BYTES
#define BIAS_OFF     (WPACK_OFF + 512ull*384ull*2ull)
#define TMP_OFF      (BIAS_OFF + 2048ull)

// ---- helpers ----
__device__ __forceinline__ u16 f2bf(float f) {
  u32 u = __builtin_bit_cast(u32, f);
  return (u16)((u + 0x7fffu + ((u >> 16) & 1u)) >> 16);   // RNE
}
__device__ __forceinline__ float bf2f(u16 h) {
  u32 u = ((u32)h) << 16;
  return __builtin_bit_cast(float, u);
}
__device__ __forceinline__ float sigf(float x) {
  float e = __builtin_amdgcn_exp2f(-1.442695041f * x);
  return __builtin_amdgcn_rcpf(1.0f + e);
}
__device__ __forceinline__ float tanhf_fast(float x) {
  x = fminf(fmaxf(x, -20.f), 20.f);       // clamp: avoid inf-inf NaN
  float e = __builtin_amdgcn_exp2f(2.885390082f * x);
  return (e - 1.0f) * __builtin_amdgcn_rcpf(e + 1.0f);
}
__device__ __forceinline__ void gload_lds16(const void* g, char* smem, u32 lds_off) {
  __builtin_amdgcn_global_load_lds(
      (const __attribute__((address_space(1))) uint32_t*)g,
      (__attribute__((address_space(3))) uint32_t*)(smem + lds_off), 16, 0, 0);
}
__device__ __forceinline__ bf16x8 ldsv(const char* smem, u32 off) {
  return *reinterpret_cast<const bf16x8*>(smem + off);    // ds_read_b128
}

// =====================================================================
// Kernel 1: pre-skew image (R1..R12-passing verbatim).
// =====================================================================
__global__ __launch_bounds__(256) void k_prepack_img(
    const float* __restrict__ image, u16* __restrict__ img_sk) {
  __shared__ float tile[128 * 33];
  const int b = blockIdx.x >> 5, n = blockIdx.x & 31;
  const int tid = threadIdx.x;
  for (int rep = 0; rep < 16; ++rep) {
    int idx = rep * 256 + tid;
    int c = idx >> 5, col = idx & 31;
    tile[c * 33 + col] = image[(((b * 128 + c) * 32 + n) << 5) + col];
  }
  __syncthreads();
  const int m = n & 7;
  for (int rep = 0; rep < 4; ++rep) {
    int idx = rep * 256 + tid;
    if (idx < NSTEP * 16) {
      int t = idx >> 4, six = idx & 15;
      bool valid = (t >= n) && (t < n + 32);
      u16x8 v;
      #pragma unroll
      for (int j = 0; j < 8; ++j) {
        int c = ((six ^ m) << 3) | j;              // inverse of read-side XOR swizzle
        v[j] = valid ? f2bf(tile[c * 33 + (t - n)]) : (u16)0;
      }
      *reinterpret_cast<u16x8*>(img_sk + (size_t)(b * NSTEP + t) * 4096 + n * 128 + six * 8) = v;
    }
  }
}

// =====================================================================
// Kernel 2: pack W, 8-wave geometry (R1..R12-passing verbatim).
// =====================================================================
__global__ __launch_bounds__(256) void k_prepack_w(
    const float* __restrict__ stos_w, const float* __restrict__ itos_w,
    u16* __restrict__ wp) {
  int pos = blockIdx.x * 256 + threadIdx.x;        // [w][mt][kk][lane][j]
  int j = pos & 7, l = (pos >> 3) & 63;
  int kk = (pos >> 9) % 12;
  int mtw = pos / 6144;
  int mt = mtw & 3, w = mtw >> 2;
  int r16 = l & 15;
  int q = r16 & 3, p = r16 >> 2;
  int c = w * 16 + mt * 4 + p;
  int o = q * 128 + c;
  int k = kk * 32 + (l >> 4) * 8 + j;
  float v;
  if (k < 128)       v = stos_w[o * 256 + k * 2 + 0];
  else if (k < 256)  v = stos_w[o * 256 + (k - 128) * 2 + 1];
  else               v = itos_w[o * 128 + (k - 256)];
  wp[pos] = f2bf(v);
}

__global__ void k_prepack_bias(const float* __restrict__ itos_b,
                               const float* __restrict__ stos_b,
                               float* __restrict__ bp) {
  int R = blockIdx.x * 256 + threadIdx.x;
  if (R >= 512) return;
  int q = R & 3, p = (R >> 2) & 3, mt = (R >> 4) & 3, w = R >> 6;
  int o = q * 128 + (w * 16 + mt * 4 + p);
  bp[R] = itos_b[o] + stos_b[o];
}

// =====================================================================
// Kernel 3: diagonal-LSTM scan — R12 (passing, 188us) with two deltas:
//   (1) software-pipelined LDS reads: b(kk+1) issued before MFMA(kk);
//       A-frags kk=10,11 prefetched during kk=6,7  -> ds_read latency
//       hides under the previous slice's MFMA block
//   (2) s_setprio(1) around the MFMA ladder (T5)
// LDS map (static 114688 B, R11/R12-verified):
//   [0,8448) hbuf0 | [8448,16896) hbuf1 | [16896,18944) bias(init only)
//   [32768,49152) imgbuf x2 (8KB each)  | [49152,114688) A-frags kk=10,11
// =====================================================================
__global__ __attribute__((amdgpu_waves_per_eu(2, 2)))
__launch_bounds__(512, 2) void k_scan(
    const u16* __restrict__ img_sk, const u16* __restrict__ wpack,
    const float* __restrict__ biasp, const float* __restrict__ h0,
    const float* __restrict__ c0, u16* __restrict__ tmp) {
  __shared__ char smem[114688];
  const int b = blockIdx.x;
  const int tid = threadIdx.x;
  const int w = tid >> 6, lane = tid & 63;
  const int p = (lane >> 4) & 3, n0 = lane & 15;

  // ---- load A fragments kk 0..9 into registers (160 regs) ----
  bf16x8 aw[4][10];
  #pragma unroll
  for (int mt = 0; mt < 4; ++mt)
    #pragma unroll
    for (int kk = 0; kk < 10; ++kk)
      aw[mt][kk] = *reinterpret_cast<const bf16x8*>(
          wpack + (size_t)(((w * 4 + mt) * 12 + kk) * 64 + lane) * 8);
  // kk=10,11 A-frags -> LDS (once; W constant)
  #pragma unroll
  for (int mt = 0; mt < 4; ++mt) {
    gload_lds16(wpack + (size_t)(((w * 4 + mt) * 12 + 10) * 64 + lane) * 8,
                smem, 49152u + (u32)w * 8192u + (u32)mt * 2048u);
    gload_lds16(wpack + (size_t)(((w * 4 + mt) * 12 + 11) * 64 + lane) * 8,
                smem, 49152u + (u32)w * 8192u + (u32)mt * 2048u + 1024u);
  }
  // preload imgbuf[0] (t=0)
  const u16* img_base = img_sk + (size_t)b * NSTEP * 4096;
  gload_lds16(img_base + (u32)tid * 8, smem, 32768u + (u32)w * 1024u);
  // bias -> LDS (staging only; consumed into registers below)
  ((float*)(smem + 16896))[tid] = biasp[tid & 511];
  // hbuf0 init: row 0 = zeros, rows 1..32 = h0 (swizzled) — verified formula
  for (int idx = tid; idx < 33 * 128; idx += 512) {
    int row = idx >> 7, c = idx & 127;
    u16 v = (row == 0) ? (u16)0 : f2bf(h0[c * 32 + (row - 1)]);
    u32 a = (u32)(row << 8) | (u32)((((c >> 3) ^ (row & 7)) << 4) | ((c & 7) << 1));
    *(u16*)(smem + a) = v;
  }
  // hbuf1 row 0 = zeros (rows 1..32 written at step 0)
  for (int idx = tid; idx < 128; idx += 512) {
    int c = idx;
    u32 a = 8448u + (u32)(((c >> 3) << 4) | ((c & 7) << 1));
    *(u16*)(smem + a) = (u16)0;
  }
  // c state in registers
  float cst[4][2];
  #pragma unroll
  for (int mt = 0; mt < 4; ++mt)
    #pragma unroll
    for (int nt = 0; nt < 2; ++nt)
      cst[mt][nt] = c0[(w * 16 + mt * 4 + p) * 32 + (nt * 16 + n0)];

  // per-lane swizzle bases (R10/R12-passing verbatim)
  const int na = n0, nb = n0 + 16;
  const u32 Ls0 = (u32)(na << 8) ^ (u32)(p << 4) ^ (u32)((na & 7) << 4);
  const u32 Ls1 = (u32)(nb << 8) ^ (u32)(p << 4) ^ (u32)((nb & 7) << 4);
  const u32 Lh0 = (u32)((na + 1) << 8) ^ (u32)(p << 4) ^ (u32)(((na + 1) & 7) << 4);
  const u32 Lh1 = (u32)((nb + 1) << 8) ^ (u32)(p << 4) ^ (u32)(((nb + 1) & 7) << 4);
  const u32 Lw0 = (u32)((na + 1) << 8) ^ (u32)(((na + 1) & 7) << 4) ^ (u32)(w << 5) ^ (u32)(p << 1);
  const u32 Lw1 = (u32)((nb + 1) << 8) ^ (u32)(((nb + 1) & 7) << 4) ^ (u32)(w << 5) ^ (u32)(p << 1);
  const u32 tmpidx = (u32)((w * 16 + p) * 32 + n0);     // + mt*128 + nt*16
  u16* tmpb = tmp + (size_t)b * NSTEP * 4096;

  __syncthreads();

  // bias into registers (once)
  f32x4 bias_r[4];
  #pragma unroll
  for (int mt = 0; mt < 4; ++mt)
    bias_r[mt] = *reinterpret_cast<const f32x4*>(smem + 16896 + ((w * 64 + mt * 16 + p * 4) << 2));

  const u32 aK10 = 49152u + (u32)w * 8192u + (u32)lane * 16u;   // + mt*2048 (+1024 for kk11)

  f32x4 acc[4][2];
  u16 hb[8];

  #pragma unroll 1
  for (int t = 0; t < NSTEP; ++t) {
    // deferred tmp stores for step t-1
    if (t) {
      #pragma unroll
      for (int mt = 0; mt < 4; ++mt)
        #pragma unroll
        for (int nt = 0; nt < 2; ++nt)
          tmpb[(size_t)(t - 1) * 4096 + tmpidx + mt * 128 + nt * 16] = hb[mt * 2 + nt];
    }
    // prefetch next image column into the other imgbuf
    if (t < NSTEP - 1)
      gload_lds16(img_base + (size_t)(t + 1) * 4096 + (u32)tid * 8,
                  smem, 32768u + (u32)(((t + 1) & 1) << 13) + (u32)w * 1024u);
    // acc = bias (from registers)
    #pragma unroll
    for (int mt = 0; mt < 4; ++mt) {
      acc[mt][0] = bias_r[mt]; acc[mt][1] = bias_r[mt];
    }

    const u32 hbb = (u32)((t & 1) ? 8448u : 0u);          // hbuf read base
    const u32 ib  = 32768u + (u32)((t & 1) << 13);

    // B-address generator for slice kk (compile-time kk under full unroll)
    auto baddr0 = [&](int kk) -> u32 {
      return (kk < 4) ? hbb + (Ls0 ^ (u32)(kk << 6))
           : (kk < 8) ? hbb + (Lh0 ^ (u32)((kk - 4) << 6))
                      : ib  + (Ls0 ^ (u32)((kk - 8) << 6));
    };
    auto baddr1 = [&](int kk) -> u32 {
      return (kk < 4) ? hbb + (Ls1 ^ (u32)(kk << 6))
           : (kk < 8) ? hbb + (Lh1 ^ (u32)((kk - 4) << 6))
                      : ib  + (Ls1 ^ (u32)((kk - 8) << 6));
    };

    __builtin_amdgcn_s_setprio(1);                 // favor this wave's MFMAs
    // ---- software-pipelined ladder ----
    bf16x8 cb0 = ldsv(smem, baddr0(0));
    bf16x8 cb1 = ldsv(smem, baddr1(0));
    bf16x8 a10[4], a11[4];                          // kk=10,11 A prefetch
    #pragma unroll
    for (int kk = 0; kk < 12; ++kk) {
      bf16x8 b0 = cb0, b1 = cb1;
      if (kk + 1 < 12) {                            // issue next B reads first
        cb0 = ldsv(smem, baddr0(kk + 1));
        cb1 = ldsv(smem, baddr1(kk + 1));
      }
      if (kk == 6) {
        #pragma unroll
        for (int mt = 0; mt < 4; ++mt) a10[mt] = ldsv(smem, aK10 + (u32)mt * 2048u);
      }
      if (kk == 7) {
        #pragma unroll
        for (int mt = 0; mt < 4; ++mt) a11[mt] = ldsv(smem, aK10 + (u32)mt * 2048u + 1024u);
      }
      #pragma unroll
      for (int mt = 0; mt < 4; ++mt) {
        bf16x8 a = (kk < 10) ? aw[mt][kk] : (kk == 10 ? a10[mt] : a11[mt]);
        acc[mt][0] = __builtin_amdgcn_mfma_f32_16x16x32_bf16(a, b0, acc[mt][0], 0, 0, 0);
        acc[mt][1] = __builtin_amdgcn_mfma_f32_16x16x32_bf16(a, b1, acc[mt][1], 0, 0, 0);
      }
    }
    __builtin_amdgcn_s_setprio(0);                 // low prio during VALU tail

    // ---- activations (regs j = i,g,f,o of one (c,s)) ----
    #pragma unroll
    for (int mt = 0; mt < 4; ++mt)
      #pragma unroll
      for (int nt = 0; nt < 2; ++nt) {
        f32x4 g4 = acc[mt][nt];
        float si = sigf(g4[0]);
        float tg = tanhf_fast(g4[1]);
        float sf = sigf(g4[2]);
        float so = sigf(g4[3]);
        float cp = cst[mt][nt];
        cst[mt][nt] = sf * cp + si * tg;   // c_new
        hb[mt * 2 + nt] = f2bf(cp * so);   // h_new = c_prev * sig(o)  (per reference)
      }
    // write h(t) into the OTHER hbuf (rows n+1); this step read from hbb
    {
      const u32 hwb = (u32)((t & 1) ? 0u : 8448u);
      #pragma unroll
      for (int mt = 0; mt < 4; ++mt)
        #pragma unroll
        for (int nt = 0; nt < 2; ++nt) {
          u32 a = hwb + ((nt ? Lw1 : Lw0) ^ (u32)((mt >= 2) ? 16u : 0u) ^ (u32)((mt & 1) << 3));
          *(u16*)(smem + a) = hb[mt * 2 + nt];
        }
    }
    __syncthreads();   // single barrier: h(t) + img(t+1) visible for step t+1
  }
  // final step's tmp stores
  #pragma unroll
  for (int mt = 0; mt < 4; ++mt)
    #pragma unroll
    for (int nt = 0; nt < 2; ++nt)
      tmpb[(size_t)(NSTEP - 1) * 4096 + tmpidx + mt * 128 + nt * 16] = hb[mt * 2 + nt];
}

// =====================================================================
// Kernel 4: unskew-transpose tmp -> out (R3..R12-passing verbatim).
// =====================================================================
__global__ __launch_bounds__(256) void k_unskew(
    const u16* __restrict__ tmp, float* __restrict__ out) {
  __shared__ float tile[8192];                 // [cl][s][j] = cl*1024+s*32+j
  const int b = blockIdx.x >> 4, c8 = blockIdx.x & 15;
  const int tid = threadIdx.x;
  const int cl = tid >> 5, s = tid & 31;
  const u16* tb = tmp + (size_t)b * NSTEP * 4096 + (u32)(c8 * 256 + cl * 32 + s);
  for (int t = 0; t < NSTEP; ++t) {
    u16 v = tb[t * 4096];
    int j = t - s;
    if ((unsigned)j < 32u) tile[cl * 1024 + s * 32 + j] = bf2f(v);
  }
  __syncthreads();
  float* op = out + (size_t)b * 131072 + (u32)(c8 * 8192);
  #pragma unroll
  for (int rep = 0; rep < 8; ++rep)
    *(f32x4*)(op + rep * 1024 + tid * 4) = *(const f32x4*)(tile + rep * 1024 + tid * 4);
}

// =====================================================================
extern "C" void kernel_launch(void* const* d_in, const int* in_sizes, int n_in,
                              void* d_out, int out_size, void* d_ws, size_t ws_size,
                              hipStream_t stream) {
  const float* image  = (const float*)d_in[0];
  const float* itos_w = (const float*)d_in[1];
  const float* itos_b = (const float*)d_in[2];
  const float* stos_w = (const float*)d_in[3];
  const float* stos_b = (const float*)d_in[4];
  const float* h0     = (const float*)d_in[5];
  const float* c0     = (const float*)d_in[6];
  (void)in_sizes; (void)n_in; (void)out_size; (void)ws_size;

  char* ws = (char*)d_ws;
  u16*   img_sk = (u16*)(ws);
  u16*   wpack  = (u16*)(ws + WPACK_OFF);
  float* biasp  = (float*)(ws + BIAS_OFF);
  u16*   tmp    = (u16*)(ws + TMP_OFF);

  k_prepack_img <<<4096, 256, 0, stream>>>(image, img_sk);
  k_prepack_w   <<<768, 256, 0, stream>>>(stos_w, itos_w, wpack);
  k_prepack_bias<<<2, 256, 0, stream>>>(itos_b, stos_b, biasp);
  k_scan        <<<128, 512, 0, stream>>>(img_sk, wpack, biasp, h0, c0, tmp);
  k_unskew      <<<2048, 256, 0, stream>>>(tmp, (float*)d_out);
}

// Round 16
// 241.388 us; speedup vs baseline: 2.7756x; 1.0101x over previous
//
#include <hip/hip_runtime.h>
#include <stdint.h>

typedef __bf16 bf16x8 __attribute__((ext_vector_type(8)));
typedef float f32x4 __attribute__((ext_vector_type(4)));
typedef float f32x16 __attribute__((ext_vector_type(16)));
typedef uint16_t u16;
typedef uint32_t u32;
typedef u16 u16x8 __attribute__((ext_vector_type(8)));
typedef u16 u16x4 __attribute__((ext_vector_type(4)));

#define NSTEP 63   // 2*32-1 diagonal steps

// ---- workspace layout (bytes) ----
// img_sk : [128][63][4096] bf16 (pre-skewed, pre-swizzled; R1-verified)
// wpack  : [8][2][25][64][8] bf16 (32x32x16 A-frags of W, K=400 incl bias col)
// tmp    : [128][63][128][32] bf16
#define IMG_SK_BYTES (128ull*NSTEP*4096ull*2ull)
#define WPACK_OFF    IMG_SK_BYTES
#define TMP_OFF      (WPACK_OFF + 8ull*2ull*25ull*64ull*8ull*2ull)

// ---- helpers ----
__device__ __forceinline__ u16 f2bf(float f) {
  u32 u = __builtin_bit_cast(u32, f);
  return (u16)((u + 0x7fffu + ((u >> 16) & 1u)) >> 16);   // RNE
}
__device__ __forceinline__ float bf2f(u16 h) {
  u32 u = ((u32)h) << 16;
  return __builtin_bit_cast(float, u);
}
__device__ __forceinline__ float sigf(float x) {
  float e = __builtin_amdgcn_exp2f(-1.442695041f * x);
  return __builtin_amdgcn_rcpf(1.0f + e);
}
__device__ __forceinline__ float tanhf_fast(float x) {
  x = fminf(fmaxf(x, -20.f), 20.f);       // clamp: avoid inf-inf NaN
  float e = __builtin_amdgcn_exp2f(2.885390082f * x);
  return (e - 1.0f) * __builtin_amdgcn_rcpf(e + 1.0f);
}
__device__ __forceinline__ void gload_lds16(const void* g, char* smem, u32 lds_off) {
  __builtin_amdgcn_global_load_lds(
      (const __attribute__((address_space(1))) uint32_t*)g,
      (__attribute__((address_space(3))) uint32_t*)(smem + lds_off), 16, 0, 0);
}
__device__ __forceinline__ bf16x8 ldsv(const char* smem, u32 off) {
  return *reinterpret_cast<const bf16x8*>(smem + off);    // ds_read_b128
}

// =====================================================================
// Kernel 1: pre-skew image (R1..R15-passing verbatim).
// =====================================================================
__global__ __launch_bounds__(256) void k_prepack_img(
    const float* __restrict__ image, u16* __restrict__ img_sk) {
  __shared__ float tile[128 * 33];
  const int b = blockIdx.x >> 5, n = blockIdx.x & 31;
  const int tid = threadIdx.x;
  for (int rep = 0; rep < 16; ++rep) {
    int idx = rep * 256 + tid;
    int c = idx >> 5, col = idx & 31;
    tile[c * 33 + col] = image[(((b * 128 + c) * 32 + n) << 5) + col];
  }
  __syncthreads();
  const int m = n & 7;
  for (int rep = 0; rep < 4; ++rep) {
    int idx = rep * 256 + tid;
    if (idx < NSTEP * 16) {
      int t = idx >> 4, six = idx & 15;
      bool valid = (t >= n) && (t < n + 32);
      u16x8 v;
      #pragma unroll
      for (int j = 0; j < 8; ++j) {
        int c = ((six ^ m) << 3) | j;              // inverse of read-side XOR swizzle
        v[j] = valid ? f2bf(tile[c * 33 + (t - n)]) : (u16)0;
      }
      *reinterpret_cast<u16x8*>(img_sk + (size_t)(b * NSTEP + t) * 4096 + n * 128 + six * 8) = v;
    }
  }
}

// =====================================================================
// Kernel 2: pack W as 32x32x16 A-fragments, K=400 (384 real + bias col).
// wp[w][mt][kappa][lane][j]: row32 = lane&31, k = kappa*16 + (lane>>5)*8 + j.
// Permutation: q=row32&3, hi=(row32>>2)&1, blk=row32>>3,
//              channel c = w*16 + mt*8 + hi*4 + blk, orig row o = q*128+c.
// K axis: [0,128)=stos_w[:,:,0], [128,256)=stos_w[:,:,1], [256,384)=itos_w,
//         k==384 -> itos_b+stos_b (ones-column bias), else 0.
// =====================================================================
__global__ __launch_bounds__(256) void k_prepack_w(
    const float* __restrict__ stos_w, const float* __restrict__ itos_w,
    const float* __restrict__ itos_b, const float* __restrict__ stos_b,
    u16* __restrict__ wp) {
  int pos = blockIdx.x * 256 + threadIdx.x;        // [w][mt][kappa][lane][j]
  if (pos >= 204800) return;
  int j = pos & 7, l = (pos >> 3) & 63;
  int idx2 = pos >> 9;
  int kap = idx2 % 25;
  int wm = idx2 / 25;
  int mt = wm & 1, w = wm >> 1;
  int row32 = l & 31, kh = l >> 5;
  int k = kap * 16 + kh * 8 + j;
  int q = row32 & 3, hb_ = (row32 >> 2) & 1, blk = row32 >> 3;
  int c = w * 16 + mt * 8 + hb_ * 4 + blk;
  int o = q * 128 + c;
  float v;
  if (k < 128)       v = stos_w[o * 256 + k * 2 + 0];
  else if (k < 256)  v = stos_w[o * 256 + (k - 128) * 2 + 1];
  else if (k < 384)  v = itos_w[o * 128 + (k - 256)];
  else if (k == 384) v = itos_b[o] + stos_b[o];
  else               v = 0.0f;
  wp[pos] = f2bf(v);
}

// =====================================================================
// Kernel 3: diagonal-LSTM scan, 32x32x16 MFMA shape.
//   8 waves x (M=64 as 2 m-tiles of 32); N=32 in ONE tile (no nt split).
//   K = 25 slices of 16; slices 0..19 in registers (160 regs, = R10/R12
//   geometry), 20..24 in LDS. Bias enters via slice 24 (ones column).
//   Single barrier/step + hbuf dbuf (R11/R12-verified skeleton).
// LDS map (static 131072 B):
//   [0,8448) hbuf0 | [8448,16896) hbuf1 | [16896,16928) ones const
//   [32768,49152) imgbuf x2 (8KB each)
//   [49152,131072) A-frags kap 20..24: w*10240 + (mt*5+(kap-20))*1024 + lane*16
// =====================================================================
__global__ __attribute__((amdgpu_waves_per_eu(2, 2)))
__launch_bounds__(512, 2) void k_scan(
    const u16* __restrict__ img_sk, const u16* __restrict__ wpack,
    const float* __restrict__ h0, const float* __restrict__ c0,
    u16* __restrict__ tmp) {
  __shared__ char smem[131072];
  const int b = blockIdx.x;
  const int tid = threadIdx.x;
  const int w = tid >> 6, lane = tid & 63;
  const int s = lane & 31, hi = lane >> 5;

  // ---- A-slices 0..19 into registers (160 regs) ----
  bf16x8 aw[2][20];
  #pragma unroll
  for (int mt = 0; mt < 2; ++mt)
    #pragma unroll
    for (int kp = 0; kp < 20; ++kp)
      aw[mt][kp] = *reinterpret_cast<const bf16x8*>(
          wpack + (size_t)(((w * 2 + mt) * 25 + kp) * 64 + lane) * 8);
  // A-slices 20..24 -> LDS (once; W constant)
  #pragma unroll
  for (int mt = 0; mt < 2; ++mt)
    #pragma unroll
    for (int kL = 0; kL < 5; ++kL)
      gload_lds16(wpack + (size_t)(((w * 2 + mt) * 25 + 20 + kL) * 64 + lane) * 8,
                  smem, 49152u + (u32)w * 10240u + (u32)(mt * 5 + kL) * 1024u);
  // preload imgbuf[0] (t=0) — R12-verbatim staging
  const u16* img_base = img_sk + (size_t)b * NSTEP * 4096;
  gload_lds16(img_base + (u32)tid * 8, smem, 32768u + (u32)w * 1024u);
  // ones-column B fragment constant: hi=0 chunk {1.0bf16,0...}, hi=1 zeros
  if (tid < 16) ((u16*)(smem + 16896))[tid] = (tid == 0) ? (u16)0x3F80 : (u16)0;
  // hbuf0 init: row 0 = zeros, rows 1..32 = h0 (swizzled) — verified formula
  for (int idx = tid; idx < 33 * 128; idx += 512) {
    int row = idx >> 7, c = idx & 127;
    u16 v = (row == 0) ? (u16)0 : f2bf(h0[c * 32 + (row - 1)]);
    u32 a = (u32)(row << 8) | (u32)((((c >> 3) ^ (row & 7)) << 4) | ((c & 7) << 1));
    *(u16*)(smem + a) = v;
  }
  // hbuf1 row 0 = zeros
  for (int idx = tid; idx < 128; idx += 512) {
    int c = idx;
    u32 a = 8448u + (u32)(((c >> 3) << 4) | ((c & 7) << 1));
    *(u16*)(smem + a) = (u16)0;
  }
  // c state: cst[mt][blk] for channel c = w*16+mt*8+hi*4+blk, col s
  float cst[2][4];
  #pragma unroll
  for (int mt = 0; mt < 2; ++mt)
    #pragma unroll
    for (int blk = 0; blk < 4; ++blk)
      cst[mt][blk] = c0[(w * 16 + mt * 8 + hi * 4 + blk) * 32 + s];

  // per-lane B bases: addr(kap) = base ^ (kap'<<5); chunk=(kap*2+hi)^(row&7)
  const u32 Bsh = ((u32)s << 8) + ((((u32)hi) ^ (u32)(s & 7)) << 4);          // rows s
  const u32 Bh  = ((u32)(s + 1) << 8) + ((((u32)hi) ^ (u32)((s + 1) & 7)) << 4); // rows s+1
  // h-write base (mt=0): row s+1, chunk (w*2)^((s+1)&7), intra hi*8; mt=1 -> ^16
  const u32 Wb0 = ((u32)(s + 1) << 8) + ((((u32)(w << 1)) ^ (u32)((s + 1) & 7)) << 4) + ((u32)hi << 3);
  const u32 aLb = 49152u + (u32)w * 10240u + (u32)lane * 16u;   // + (mt*5+kL)*1024
  const u32 tmpidx = (u32)(w * 512 + hi * 128 + s);             // + mt*256 + blk*32
  u16* tmpb = tmp + (size_t)b * NSTEP * 4096;

  __syncthreads();   // drains init DMAs (vmcnt) + LDS writes

  f32x16 acc[2];
  u16 hb[2][4];

  #pragma unroll 1
  for (int t = 0; t < NSTEP; ++t) {
    // deferred tmp stores for step t-1
    if (t) {
      #pragma unroll
      for (int mt = 0; mt < 2; ++mt)
        #pragma unroll
        for (int blk = 0; blk < 4; ++blk)
          tmpb[(size_t)(t - 1) * 4096 + tmpidx + mt * 256 + blk * 32] = hb[mt][blk];
    }
    // prefetch next image column into the other imgbuf (R12-verbatim)
    if (t < NSTEP - 1)
      gload_lds16(img_base + (size_t)(t + 1) * 4096 + (u32)tid * 8,
                  smem, 32768u + (u32)(((t + 1) & 1) << 13) + (u32)w * 1024u);

    const u32 hbb = (u32)((t & 1) ? 8448u : 0u);          // hbuf read base
    const u32 ib  = 32768u + (u32)((t & 1) << 13);

    __builtin_amdgcn_s_setprio(1);
    // ---- bias slice (kap=24) first: acc = bias via ones column, C=0 ----
    {
      bf16x8 bOnes = ldsv(smem, 16896u + ((u32)hi << 4));
      f32x16 z = {};
      #pragma unroll
      for (int mt = 0; mt < 2; ++mt) {
        bf16x8 a = ldsv(smem, aLb + (u32)(mt * 5 + 4) * 1024u);
        acc[mt] = __builtin_amdgcn_mfma_f32_32x32x16_bf16(a, bOnes, z, 0, 0, 0);
      }
    }
    // ---- K ladder: kap 0..23 ----
    #pragma unroll
    for (int kp = 0; kp < 24; ++kp) {
      bf16x8 bv;
      if (kp < 8)       bv = ldsv(smem, hbb + (Bsh ^ ((u32)kp << 5)));          // shifted h
      else if (kp < 16) bv = ldsv(smem, hbb + (Bh ^ ((u32)(kp - 8) << 5)));     // h
      else              bv = ldsv(smem, ib + (Bsh ^ ((u32)(kp - 16) << 5)));    // image
      #pragma unroll
      for (int mt = 0; mt < 2; ++mt) {
        bf16x8 a = (kp < 20) ? aw[mt][kp]
                             : ldsv(smem, aLb + (u32)(mt * 5 + (kp - 20)) * 1024u);
        acc[mt] = __builtin_amdgcn_mfma_f32_32x32x16_bf16(a, bv, acc[mt], 0, 0, 0);
      }
    }
    __builtin_amdgcn_s_setprio(0);

    // ---- activations: acc[mt] regs = q + blk*4 (q: i,g,f,o) ----
    #pragma unroll
    for (int mt = 0; mt < 2; ++mt)
      #pragma unroll
      for (int blk = 0; blk < 4; ++blk) {
        float gi = acc[mt][blk * 4 + 0];
        float gg = acc[mt][blk * 4 + 1];
        float gf = acc[mt][blk * 4 + 2];
        float go = acc[mt][blk * 4 + 3];
        float si = sigf(gi);
        float tg = tanhf_fast(gg);
        float sf = sigf(gf);
        float so = sigf(go);
        float cp = cst[mt][blk];
        cst[mt][blk] = sf * cp + si * tg;   // c_new
        hb[mt][blk] = f2bf(cp * so);        // h_new = c_prev * sig(o)
      }
    // ---- h-write: 2 x ds_write_b64 (4 contiguous channels each) ----
    {
      const u32 hwb = (u32)((t & 1) ? 0u : 8448u);
      u16x4 p0 = {hb[0][0], hb[0][1], hb[0][2], hb[0][3]};
      u16x4 p1 = {hb[1][0], hb[1][1], hb[1][2], hb[1][3]};
      *(u16x4*)(smem + (hwb + Wb0)) = p0;
      *(u16x4*)(smem + ((hwb + Wb0) ^ 16u)) = p1;
    }
    __syncthreads();   // single barrier: h(t) + img(t+1) visible for t+1
  }
  // final step's tmp stores
  #pragma unroll
  for (int mt = 0; mt < 2; ++mt)
    #pragma unroll
    for (int blk = 0; blk < 4; ++blk)
      tmpb[(size_t)(NSTEP - 1) * 4096 + tmpidx + mt * 256 + blk * 32] = hb[mt][blk];
}

// =====================================================================
// Kernel 4: unskew-transpose tmp -> out (R3..R15-passing verbatim).
// =====================================================================
__global__ __launch_bounds__(256) void k_unskew(
    const u16* __restrict__ tmp, float* __restrict__ out) {
  __shared__ float tile[8192];                 // [cl][s][j] = cl*1024+s*32+j
  const int b = blockIdx.x >> 4, c8 = blockIdx.x & 15;
  const int tid = threadIdx.x;
  const int cl = tid >> 5, s = tid & 31;
  const u16* tb = tmp + (size_t)b * NSTEP * 4096 + (u32)(c8 * 256 + cl * 32 + s);
  for (int t = 0; t < NSTEP; ++t) {
    u16 v = tb[t * 4096];
    int j = t - s;
    if ((unsigned)j < 32u) tile[cl * 1024 + s * 32 + j] = bf2f(v);
  }
  __syncthreads();
  float* op = out + (size_t)b * 131072 + (u32)(c8 * 8192);
  #pragma unroll
  for (int rep = 0; rep < 8; ++rep)
    *(f32x4*)(op + rep * 1024 + tid * 4) = *(const f32x4*)(tile + rep * 1024 + tid * 4);
}

// =====================================================================
extern "C" void kernel_launch(void* const* d_in, const int* in_sizes, int n_in,
                              void* d_out, int out_size, void* d_ws, size_t ws_size,
                              hipStream_t stream) {
  const float* image  = (const float*)d_in[0];
  const float* itos_w = (const float*)d_in[1];
  const float* itos_b = (const float*)d_in[2];
  const float* stos_w = (const float*)d_in[3];
  const float* stos_b = (const float*)d_in[4];
  const float* h0     = (const float*)d_in[5];
  const float* c0     = (const float*)d_in[6];
  (void)in_sizes; (void)n_in; (void)out_size; (void)ws_size;

  char* ws = (char*)d_ws;
  u16*   img_sk = (u16*)(ws);
  u16*   wpack  = (u16*)(ws + WPACK_OFF);
  u16*   tmp    = (u16*)(ws + TMP_OFF);

  k_prepack_img <<<4096, 256, 0, stream>>>(image, img_sk);
  k_prepack_w   <<<800, 256, 0, stream>>>(stos_w, itos_w, itos_b, stos_b, wpack);
  k_scan        <<<128, 512, 0, stream>>>(img_sk, wpack, h0, c0, tmp);
  k_unskew      <<<2048, 256, 0, stream>>>(tmp, (float*)d_out);
}